// Round 1
// baseline (215.976 us; speedup 1.0000x reference)
//
#include <hip/hip_runtime.h>
#include <hip/hip_bf16.h>

// GAT layer: B=2, N=2048, C_IN=128, H=16, c=8.
// out = softmax_j(mask(lrelu(lp_i + lc_j))) @ h   per (b, head)
// d_out = [out: B*N*128 floats][adj copy: B*N*N floats]
//
// K1  : h = nf@W+b  (stored transposed [B,H,N,8]) + lp/lc halves [B,H,N]
// K1b : Lmax[b,h] = max_j lc[b,h,j]   (upper-bound softmax shift -> single pass)
// K2  : flash-style aggregation; wave = 1 head x 8 i-rows; adj as ballot bitmask
//       in LDS; adj copy to d_out fused into staging.

#define B_   2
#define N_   2048
#define CIN_ 128
#define H_   16
#define C_   8

__global__ __launch_bounds__(128) void proj_kernel(
    const float* __restrict__ nf, const float* __restrict__ W,
    const float* __restrict__ bias, const float* __restrict__ a,
    float* __restrict__ hT, float* __restrict__ lpT, float* __restrict__ lcT) {
  const int row = blockIdx.x;            // b*N + n
  const int b   = row >> 11;
  const int n   = row & (N_ - 1);
  const int t   = threadIdx.x;           // output column 0..127
  __shared__ float sNf[CIN_];
  sNf[t] = nf[(long)row * CIN_ + t];
  __syncthreads();
  float acc = bias[t];
#pragma unroll 16
  for (int k = 0; k < CIN_; ++k) acc = fmaf(sNf[k], W[k * 128 + t], acc);
  const int h = t >> 3, kc = t & 7;
  hT[((long)(b * H_ + h) * N_ + n) * C_ + kc] = acc;
  // a is [H, 2c] = [16,16]; parent half a[h,0:8], child half a[h,8:16]
  float lpv = acc * a[h * 16 + kc];
  float lcv = acc * a[h * 16 + 8 + kc];
#pragma unroll
  for (int s = 1; s < 8; s <<= 1) {
    lpv += __shfl_xor(lpv, s);
    lcv += __shfl_xor(lcv, s);
  }
  if (kc == 0) {
    lpT[(long)(b * H_ + h) * N_ + n] = lpv;
    lcT[(long)(b * H_ + h) * N_ + n] = lcv;
  }
}

__global__ __launch_bounds__(256) void lmax_kernel(
    const float* __restrict__ lcT, float* __restrict__ Lmax) {
  const int bh = blockIdx.x;             // 0..31
  const int t  = threadIdx.x;            // 256 threads
  float m = -INFINITY;
  for (int j = t; j < N_; j += 256) m = fmaxf(m, lcT[(long)bh * N_ + j]);
#pragma unroll
  for (int s = 1; s < 64; s <<= 1) m = fmaxf(m, __shfl_xor(m, s));
  __shared__ float sm[4];
  if ((t & 63) == 0) sm[t >> 6] = m;
  __syncthreads();
  if (t == 0) Lmax[bh] = fmaxf(fmaxf(sm[0], sm[1]), fmaxf(sm[2], sm[3]));
}

__global__ __launch_bounds__(512) void attn_kernel(
    const float* __restrict__ adj, const float* __restrict__ hT,
    const float* __restrict__ lpT, const float* __restrict__ lcT,
    const float* __restrict__ Lmax, float* __restrict__ out,
    float* __restrict__ adj_out) {
  const int hgroup = blockIdx.x & 1;     // which 8 heads
  const int tile   = blockIdx.x >> 1;
  const int b      = tile >> 8;          // 256 i-tiles per batch
  const int i0     = (tile & 255) * 8;
  const int tid    = threadIdx.x;
  const int wid    = tid >> 6;           // 0..7
  const int lane   = tid & 63;

  __shared__ unsigned long long sMask[8][32];

  // Stage adjacency rows as ballot bitmasks; fuse the adj copy to d_out.
  {
    const int r = wid;                   // wave w stages row r
    const float* arow = adj + ((long)(b * N_ + i0 + r)) * N_;
    float* orow = adj_out + ((long)(b * N_ + i0 + r)) * N_;
#pragma unroll
    for (int ch = 0; ch < 32; ++ch) {
      const int j = ch * 64 + lane;
      const float v = arow[j];
      if (hgroup == 0) orow[j] = v;      // only one head-group writes the copy
      const unsigned long long mk = __ballot(v == 1.0f);
      if (lane == 0) sMask[r][ch] = mk;
    }
  }
  __syncthreads();

  const int  hw   = hgroup * 8 + wid;    // this wave's head
  const long base = (long)(b * H_ + hw) * N_;
  const float Lm  = Lmax[b * H_ + hw];

  float lpv[8], mrow[8], lrow[8], accv[8][8];
#pragma unroll
  for (int r = 0; r < 8; ++r) {
    lpv[r] = lpT[base + i0 + r];
    const float tv = lpv[r] + Lm;
    mrow[r] = tv > 0.0f ? tv : 0.2f * tv;   // lrelu(lp + max_j lc) >= row max
    lrow[r] = 0.0f;
#pragma unroll
    for (int k = 0; k < 8; ++k) accv[r][k] = 0.0f;
  }

  for (int jj = 0; jj < 32; ++jj) {
    const int j = jj * 64 + lane;
    const float lcj = lcT[base + j];
    const float4 h0 = *(const float4*)(hT + (base + j) * C_);
    const float4 h1 = *(const float4*)(hT + (base + j) * C_ + 4);
#pragma unroll
    for (int r = 0; r < 8; ++r) {
      const unsigned long long mk = sMask[r][jj];
      float tv = lpv[r] + lcj;
      tv = tv > 0.0f ? tv : 0.2f * tv;
      const float e = ((mk >> lane) & 1ull) ? __expf(tv - mrow[r]) : 0.0f;
      lrow[r] += e;
      accv[r][0] = fmaf(e, h0.x, accv[r][0]);
      accv[r][1] = fmaf(e, h0.y, accv[r][1]);
      accv[r][2] = fmaf(e, h0.z, accv[r][2]);
      accv[r][3] = fmaf(e, h0.w, accv[r][3]);
      accv[r][4] = fmaf(e, h1.x, accv[r][4]);
      accv[r][5] = fmaf(e, h1.y, accv[r][5]);
      accv[r][6] = fmaf(e, h1.z, accv[r][6]);
      accv[r][7] = fmaf(e, h1.w, accv[r][7]);
    }
  }

  // Full 64-lane butterfly: every lane ends with the complete sums.
#pragma unroll
  for (int s = 1; s < 64; s <<= 1) {
#pragma unroll
    for (int r = 0; r < 8; ++r) {
      lrow[r] += __shfl_xor(lrow[r], s);
#pragma unroll
      for (int k = 0; k < 8; ++k) accv[r][k] += __shfl_xor(accv[r][k], s);
    }
  }

  // lane L -> output element (row rsel, feature ksel); all 64 lanes write.
  const int rsel = lane >> 3, ksel = lane & 7;
  float av = 0.0f, lv = 1.0f;
#pragma unroll
  for (int r = 0; r < 8; ++r) {
    if (rsel == r) lv = lrow[r];
#pragma unroll
    for (int k = 0; k < 8; ++k)
      if (rsel == r && ksel == k) av = accv[r][k];
  }
  out[((long)(b * N_ + i0 + rsel)) * (H_ * C_) + hw * C_ + ksel] = av / lv;
}

extern "C" void kernel_launch(void* const* d_in, const int* in_sizes, int n_in,
                              void* d_out, int out_size, void* d_ws, size_t ws_size,
                              hipStream_t stream) {
  const float* nf   = (const float*)d_in[0];
  const float* adj  = (const float*)d_in[1];
  const float* W    = (const float*)d_in[2];
  const float* bias = (const float*)d_in[3];
  const float* a    = (const float*)d_in[4];

  float* out     = (float*)d_out;
  float* adj_out = out + (long)B_ * N_ * H_ * C_;   // 524288 offset

  float* ws   = (float*)d_ws;
  float* hT   = ws;                        // B*H*N*C = 524288 floats
  float* lpT  = ws + 524288;               // B*H*N   =  65536
  float* lcT  = ws + 589824;               // B*H*N   =  65536
  float* LmaxA = ws + 655360;              // B*H     =     32

  hipLaunchKernelGGL(proj_kernel, dim3(B_ * N_), dim3(128), 0, stream,
                     nf, W, bias, a, hT, lpT, lcT);
  hipLaunchKernelGGL(lmax_kernel, dim3(B_ * H_), dim3(256), 0, stream, lcT, LmaxA);
  hipLaunchKernelGGL(attn_kernel, dim3(B_ * (N_ / 8) * 2), dim3(512), 0, stream,
                     adj, hT, lpT, lcT, LmaxA, out, adj_out);
}

// Round 2
// 161.967 us; speedup vs baseline: 1.3335x; 1.3335x over previous
//
#include <hip/hip_runtime.h>
#include <hip/hip_bf16.h>

// GAT layer: B=2, N=2048, C_IN=128, H=16, c=8.
// Key identity: exp(lrelu(lp_i+lc_j) - m_i) = max(P1_i*Q1_j, P2_i*Q2_j)
//   P1=exp(lp+Lm-mrow), P2=exp(0.2(lp+Lm)-mrow), Q1=exp(lc-Lm), Q2=exp(0.2(lc-Lm))
//   (all <= 1, overflow-safe; masking = multiply by adjacency 0/1 float)
// d_out = [out: B*N*128][adj copy: B*N*N]

#define B_   2
#define N_   2048
#define CIN_ 128
#define H_   16
#define C_   8

__global__ __launch_bounds__(128) void proj_kernel(
    const float* __restrict__ nf, const float* __restrict__ W,
    const float* __restrict__ bias, const float* __restrict__ a,
    float* __restrict__ hT, float* __restrict__ lpT, float* __restrict__ lcT) {
  const int row0 = blockIdx.x * 8;       // 8 consecutive global rows (b*N+n)
  const int t    = threadIdx.x;          // output column 0..127
  __shared__ float sNf[8][CIN_];
  {
    const float4* src = (const float4*)(nf + (long)row0 * CIN_);
    float4* dst = (float4*)(&sNf[0][0]);
    dst[t]       = src[t];
    dst[t + 128] = src[t + 128];
  }
  __syncthreads();
  float acc[8];
#pragma unroll
  for (int r = 0; r < 8; ++r) acc[r] = bias[t];
#pragma unroll 8
  for (int k = 0; k < CIN_; ++k) {
    const float w = W[k * 128 + t];
#pragma unroll
    for (int r = 0; r < 8; ++r) acc[r] = fmaf(sNf[r][k], w, acc[r]);
  }
  const int h = t >> 3, kc = t & 7;
  const float ap = a[h * 16 + kc], ac = a[h * 16 + 8 + kc];
#pragma unroll
  for (int r = 0; r < 8; ++r) {
    const int row = row0 + r;
    const int b = row >> 11, n = row & (N_ - 1);
    hT[((long)(b * H_ + h) * N_ + n) * C_ + kc] = acc[r];
    float lpv = acc[r] * ap, lcv = acc[r] * ac;
#pragma unroll
    for (int s = 1; s < 8; s <<= 1) {
      lpv += __shfl_xor(lpv, s);
      lcv += __shfl_xor(lcv, s);
    }
    if (kc == 0) {
      lpT[(long)(b * H_ + h) * N_ + n] = lpv;
      lcT[(long)(b * H_ + h) * N_ + n] = lcv;
    }
  }
}

__global__ __launch_bounds__(512, 4) void attn_kernel(
    const float* __restrict__ adj, const float* __restrict__ hT,
    const float* __restrict__ lpT, const float* __restrict__ lcT,
    float* __restrict__ out, float* __restrict__ adj_out) {
  const int hgroup = blockIdx.x & 1;     // which 8 heads
  const int tile   = blockIdx.x >> 1;
  const int b      = tile >> 8;          // 256 i-tiles per batch
  const int i0     = (tile & 255) * 8;
  const int tid    = threadIdx.x;
  const int wid    = tid >> 6;           // 0..7
  const int lane   = tid & 63;

  __shared__ float sAdj[8][N_];          // 64 KB: adjacency rows as floats

  // Stage adjacency rows (float4) + fused adj copy to d_out (hgroup 0 only).
  {
    const float4* arow = (const float4*)(adj + ((long)(b * N_ + i0 + wid)) * N_);
    float4* orow = (float4*)(adj_out + ((long)(b * N_ + i0 + wid)) * N_);
    float4* lrow4 = (float4*)(&sAdj[wid][0]);
#pragma unroll
    for (int ch = 0; ch < 8; ++ch) {
      const int idx = ch * 64 + lane;    // float4 index 0..511
      const float4 v = arow[idx];
      lrow4[idx] = v;
      if (hgroup == 0) orow[idx] = v;
    }
  }
  __syncthreads();

  const int  hw   = hgroup * 8 + wid;    // this wave's head
  const long base = (long)(b * H_ + hw) * N_;
  const float* lcp = lcT + base;
  const float4* hp = (const float4*)(hT + base * C_);

  // Per-wave Lm = max_j lc (overflow-safety shift)
  float Lm = -1e30f;
#pragma unroll
  for (int k = 0; k < 32; ++k) Lm = fmaxf(Lm, lcp[k * 64 + lane]);
#pragma unroll
  for (int s = 1; s < 64; s <<= 1) Lm = fmaxf(Lm, __shfl_xor(Lm, s));

  float P1[8], P2[8], lrow[8], acc[8][8];
#pragma unroll
  for (int r = 0; r < 8; ++r) {
    const float lp = lpT[base + i0 + r];
    const float s0 = lp + Lm;
    const float mrow = fmaxf(s0, 0.2f * s0);   // lrelu(lp+Lm) >= row max logit
    P1[r] = __expf(s0 - mrow);
    P2[r] = __expf(0.2f * s0 - mrow);
    lrow[r] = 0.0f;
#pragma unroll
    for (int k = 0; k < 8; ++k) acc[r][k] = 0.0f;
  }

  // Prefetched j-loop: no exp, no mask bit-ops in the r-loop.
  float  lc_c = lcp[lane];
  float4 h0_c = hp[lane * 2];
  float4 h1_c = hp[lane * 2 + 1];
  for (int jj = 0; jj < 32; ++jj) {
    const int jn = ((jj + 1) & 31) * 64 + lane;   // next chunk (wraps harmlessly)
    const float  lc_n = lcp[jn];
    const float4 h0_n = hp[jn * 2];
    const float4 h1_n = hp[jn * 2 + 1];

    float av[8];
#pragma unroll
    for (int r = 0; r < 8; ++r) av[r] = sAdj[r][jj * 64 + lane];

    const float tq = lc_c - Lm;
    const float Q1 = __expf(tq);
    const float Q2 = __expf(0.2f * tq);

#pragma unroll
    for (int r = 0; r < 8; ++r) {
      const float e = fmaxf(P1[r] * Q1, P2[r] * Q2) * av[r];
      lrow[r] += e;
      acc[r][0] = fmaf(e, h0_c.x, acc[r][0]);
      acc[r][1] = fmaf(e, h0_c.y, acc[r][1]);
      acc[r][2] = fmaf(e, h0_c.z, acc[r][2]);
      acc[r][3] = fmaf(e, h0_c.w, acc[r][3]);
      acc[r][4] = fmaf(e, h1_c.x, acc[r][4]);
      acc[r][5] = fmaf(e, h1_c.y, acc[r][5]);
      acc[r][6] = fmaf(e, h1_c.z, acc[r][6]);
      acc[r][7] = fmaf(e, h1_c.w, acc[r][7]);
    }
    lc_c = lc_n; h0_c = h0_n; h1_c = h1_n;
  }

  // Full 64-lane butterfly reduction.
#pragma unroll
  for (int s = 1; s < 64; s <<= 1) {
#pragma unroll
    for (int r = 0; r < 8; ++r) {
      lrow[r] += __shfl_xor(lrow[r], s);
#pragma unroll
      for (int k = 0; k < 8; ++k) acc[r][k] += __shfl_xor(acc[r][k], s);
    }
  }

  const int rsel = lane >> 3, ksel = lane & 7;
  float av = 0.0f, lv = 1.0f;
#pragma unroll
  for (int r = 0; r < 8; ++r) {
    if (rsel == r) lv = lrow[r];
#pragma unroll
    for (int k = 0; k < 8; ++k)
      if (rsel == r && ksel == k) av = acc[r][k];
  }
  out[((long)(b * N_ + i0 + rsel)) * (H_ * C_) + hw * C_ + ksel] = av / lv;
}

extern "C" void kernel_launch(void* const* d_in, const int* in_sizes, int n_in,
                              void* d_out, int out_size, void* d_ws, size_t ws_size,
                              hipStream_t stream) {
  const float* nf   = (const float*)d_in[0];
  const float* adj  = (const float*)d_in[1];
  const float* W    = (const float*)d_in[2];
  const float* bias = (const float*)d_in[3];
  const float* a    = (const float*)d_in[4];

  float* out     = (float*)d_out;
  float* adj_out = out + (long)B_ * N_ * H_ * C_;   // 524288 offset

  float* ws  = (float*)d_ws;
  float* hT  = ws;                        // B*H*N*C = 524288 floats
  float* lpT = ws + 524288;               // B*H*N   =  65536
  float* lcT = ws + 589824;               // B*H*N   =  65536

  hipLaunchKernelGGL(proj_kernel, dim3(B_ * N_ / 8), dim3(128), 0, stream,
                     nf, W, bias, a, hT, lpT, lcT);
  hipLaunchKernelGGL(attn_kernel, dim3(B_ * (N_ / 8) * 2), dim3(512), 0, stream,
                     adj, hT, lpT, lcT, out, adj_out);
}